// Round 4
// baseline (175.732 us; speedup 1.0000x reference)
//
#include <hip/hip_runtime.h>
#include <math.h>
#include <stdint.h>

// ---------------- model constants ----------------
#define BATCH 65536
#define TB 64            // 4 waves x 16 rows (one 16x16 m-tile each), independent

typedef __fp16   fp16x2  __attribute__((ext_vector_type(2)));   // cvt_pkrtz result
typedef _Float16 half8   __attribute__((ext_vector_type(8)));
typedef float    floatx4 __attribute__((ext_vector_type(4)));

// per-wave LDS strides (halves)
#define SH 68            // hH: 64 cols + 4 pad (136B rows: distinct banks, b128 ok)
#define SM 168           // hM: 129 real cols + pads to 168 (336B rows: 16B-aligned, 2-way banks)

// packed-weight geometry (f16), FRAGMENT-ORDERED for 16x16x32:
//   element (ks, nt, lane, j) at ((ks*NT + nt)*512) + lane*8 + j
//   maps to B[k = ks*32 + (lane>>4)*8 + j][n = nt*16 + (lane&15)]
#define WIN 2048          // stage1: 1 kstep x 4 ntiles x 512 (W_in is 32x64)
#define KSA 18            // a: 16 spline ksteps (512 k) + 2 silu (64)
#define KSB 38            // b: 33 spline ksteps (1032 real k, pad to 1056) + 5 silu (129 real)
#define WA (KSA*9*512)    // 82944
#define WB (KSB*4*512)    // 77824
#define WTOT (WIN + 2*(WA+WB))   // 323584 halfs = 647168 B of d_ws

// ---------------------------------------------------------------------------
// setup: pack all weights f16 in 16x16x32-fragment order.
// Vectorized: one thread -> 8 consecutive halves (j=0..7) -> one 16B store.
// Since kb = ks*32 + (lane>>4)*8 is a multiple of 8, all 8 j's share one
// spline row i = kb>>3 -> contiguous 32B coef read.
// ---------------------------------------------------------------------------
__global__ void setup_weights(
    const float* __restrict__ W_in,
    const float* __restrict__ c0a, const float* __restrict__ sb0a, const float* __restrict__ ss0a,
    const float* __restrict__ c0b, const float* __restrict__ sb0b, const float* __restrict__ ss0b,
    const float* __restrict__ c1a, const float* __restrict__ sb1a, const float* __restrict__ ss1a,
    const float* __restrict__ c1b, const float* __restrict__ sb1b, const float* __restrict__ ss1b,
    _Float16* __restrict__ wt) {
  int e = (blockIdx.x * 256 + threadIdx.x) * 8;
  if (e >= WTOT) return;
  float v[8];
  #pragma unroll
  for (int j = 0; j < 8; ++j) v[j] = 0.0f;

  if (e < WIN) {                          // W_in [32][64]: 1 kstep, 4 n-tiles
    int nt = e >> 9;
    int l  = (e >> 3) & 63;
    int n  = nt*16 + (l & 15);
    int kb = (l >> 4) * 8;
    #pragma unroll
    for (int j = 0; j < 8; ++j) v[j] = W_in[(kb + j)*64 + n];
  } else {
    int e2   = e - WIN;
    int pair = (e2 >= WA + WB) ? 1 : 0;
    int e3   = e2 - pair * (WA + WB);
    if (e3 < WA) {                        // a-type: I=64, O=129 (9 n-tiles of 16)
      const float* coef = pair ? c1a : c0a;
      const float* sb   = pair ? sb1a : sb0a;
      const float* ss   = pair ? ss1a : ss0a;
      int ks = e3 / 4608; int r = e3 - ks*4608;   // 9*512 per kstep
      int nt = r >> 9;    int l = (r >> 3) & 63;
      int n  = nt*16 + (l & 15);
      int kb = ks*32 + (l >> 4)*8;        // multiple of 8; < 576
      if (n < 129) {
        if (kb < 512) {                   // spline: row i fixed across j
          int i = kb >> 3;
          float s = ss[i*129 + n];
          const float* cp = &coef[(i*129 + n)*8];
          #pragma unroll
          for (int j = 0; j < 8; ++j) v[j] = s * cp[j];
        } else {                          // silu rows: s = kb-512+j in [0,64)
          #pragma unroll
          for (int j = 0; j < 8; ++j) v[j] = sb[(kb - 512 + j)*129 + n];
        }
      }
    } else {                              // b-type: I=129, O=64 (4 n-tiles)
      const float* coef = pair ? c1b : c0b;
      const float* sb   = pair ? sb1b : sb0b;
      const float* ss   = pair ? ss1b : ss0b;
      int e4 = e3 - WA;
      int ks = e4 >> 11;  int r = e4 & 2047;      // 4*512 per kstep
      int nt = r >> 9;    int l = (r >> 3) & 63;
      int n  = nt*16 + (l & 15);
      int kb = ks*32 + (l >> 4)*8;        // < 1216
      if (kb < 1032) {                    // spline (kb=1024..1031 is i=128, j<8)
        int i = kb >> 3;
        float s = ss[i*64 + n];
        const float* cp = &coef[(i*64 + n)*8];
        #pragma unroll
        for (int j = 0; j < 8; ++j) v[j] = s * cp[j];
      } else if (kb >= 1056) {            // silu rows: s = kb-1056+j, guard <129
        #pragma unroll
        for (int j = 0; j < 8; ++j) {
          int si = kb - 1056 + j;
          if (si < 129) v[j] = sb[si*64 + n];
        }
      }
      // kb in [1032,1056): dead pad -> 0
    }
  }
  half8 h;
  #pragma unroll
  for (int j = 0; j < 8; ++j) h[j] = (_Float16)v[j];
  *(half8*)&wt[e] = h;
}

// ---------------------------------------------------------------------------
// feat8: 8 B-spline basis values of x as a ready A-fragment (unchanged math).
// ---------------------------------------------------------------------------
__device__ __forceinline__ half8 feat8(float x) {
  float s  = fmaf(x, 2.5f, 5.5f);          // (x+2.2)*2.5
  float mf = floorf(s);
  int   m  = (int)mf;
  float u  = s - mf;
  float t  = 1.0f - u;
  float u2 = u*u;
  float t2 = t*t;
  float w0 = t2 * (t * (1.0f/6.0f));
  float w3 = u2 * (u * (1.0f/6.0f));
  float w1 = fmaf(u2, fmaf(0.5f, u, -1.0f), 2.0f/3.0f);   // (3u^3-6u^2+4)/6
  float w2 = fmaf(t2, fmaf(0.5f, t, -1.0f), 2.0f/3.0f);   // symmetry: w1(t)
  union { fp16x2 h2[2]; uint64_t u64; } P;
  P.h2[0] = __builtin_amdgcn_cvt_pkrtz(w0, w1);
  P.h2[1] = __builtin_amdgcn_cvt_pkrtz(w2, w3);
  uint64_t T = ((unsigned)m <= 10u) ? P.u64 : 0ull;
  int A = (m << 4) - 48;                   // bit pos of T in 128-bit window
  uint64_t L  = T << (A & 63);             // valid A: {-48..112} step 16
  uint64_t R_ = T >> ((-A) & 63);
  uint64_t q0 = (A >= 0) ? ((A < 64) ? L : 0ull) : R_;
  uint64_t q1 = (A >= 64) ? L : ((A > 0) ? R_ : 0ull);
  union { uint64_t q[2]; half8 h; } R;
  R.q[0] = q0; R.q[1] = q1;
  return R.h;
}

// cheap silu: x * rcp(1+exp(-x)) — v_rcp_f32 (~1 ulp) instead of IEEE div
__device__ __forceinline__ float silu(float x) {
  return x * __builtin_amdgcn_rcpf(1.0f + __expf(-x));
}

// ---------------------------------------------------------------------------
// one KAN layer, per-wave 16 rows = one 16x16 m-tile. 16x16x32 MFMA:
// per kstep, k=32 = 4 inputs x 8 basis; lane (row=lane&15, kgrp=lane>>4)
// computes feat8(h[row][ks*4+kgrp]) -> its 8 A halves.
// NT<=4 (layer-b): depth-2 zero-copy B pipeline (proven pattern).
// NT>4 (layer-a, 9 tiles): per-kstep B loads, latency hidden by 4-wave TLP.
// ---------------------------------------------------------------------------
template<int KSPL, int KSIL, int NT, int SIN, int O, int SOUT>
__device__ __forceinline__ void kan_layer16(
    const _Float16* __restrict__ hinw, _Float16* __restrict__ houtw,
    const _Float16* __restrict__ wtl, const float* __restrict__ bias, int lane) {
  constexpr int KTOT = KSPL + KSIL;
  constexpr int NG   = KSPL / 8;            // full spline groups
  constexpr int KR   = KSPL - NG*8;         // remainder spline steps (0 or 1)
  static_assert(KR == 0 || KR == 1, "remainder must be 0/1");
  const int ln16 = lane & 15;
  const int kg   = lane >> 4;
  const half8* __restrict__ bp = (const half8*)wtl + lane;   // +lane*16B
  floatx4 acc[NT];
  #pragma unroll
  for (int j = 0; j < NT; ++j)
    #pragma unroll
    for (int el = 0; el < 4; ++el) acc[j][el] = 0.0f;

  if constexpr (NT <= 4) {
    // ---- depth-2 zero-copy pipeline (layer-b) ----
    half8 B[2][NT];
    #pragma unroll
    for (int d = 0; d < 2; ++d)
      #pragma unroll
      for (int j = 0; j < NT; ++j) B[d][j] = bp[(d*NT + j)*64];

    #pragma unroll 1
    for (int g = 0; g < NG; ++g) {
      #pragma unroll
      for (int u = 0; u < 8; ++u) {
        const int ks = g*8 + u;
        half8 A = feat8((float)hinw[ln16*SIN + ks*4 + kg]);  // input i = 4ks+kg
        #pragma unroll
        for (int j = 0; j < NT; ++j)
          acc[j] = __builtin_amdgcn_mfma_f32_16x16x32_f16(A, B[u & 1][j], acc[j], 0, 0, 0);
        #pragma unroll
        for (int j = 0; j < NT; ++j)
          B[u & 1][j] = bp[((ks + 2)*NT + j)*64];            // ks+2 <= 33 < KTOT
      }
    }
    if constexpr (KR == 1) {              // ks = 32: inputs 128..131 (pads zero-B)
      constexpr int ks = NG*8;
      half8 A = feat8((float)hinw[ln16*SIN + ks*4 + kg]);
      #pragma unroll
      for (int j = 0; j < NT; ++j)
        acc[j] = __builtin_amdgcn_mfma_f32_16x16x32_f16(A, B[ks & 1][j], acc[j], 0, 0, 0);
      #pragma unroll
      for (int j = 0; j < NT; ++j)
        B[ks & 1][j] = bp[((ks + 2)*NT + j)*64];             // 34 < 38
    }
    #pragma unroll
    for (int sk = 0; sk < KSIL; ++sk) {
      const int ks = KSPL + sk;
      half8 h8 = *(const half8*)&hinw[ln16*SIN + sk*32 + kg*8];
      union { fp16x2 h2[4]; half8 v; } Au;
      #pragma unroll
      for (int el = 0; el < 4; ++el) {
        float s0 = silu((float)h8[2*el]);
        float s1 = silu((float)h8[2*el + 1]);
        Au.h2[el] = __builtin_amdgcn_cvt_pkrtz(s0, s1);
      }
      #pragma unroll
      for (int j = 0; j < NT; ++j)
        acc[j] = __builtin_amdgcn_mfma_f32_16x16x32_f16(Au.v, B[ks & 1][j], acc[j], 0, 0, 0);
      const int nks = (ks + 2 < KTOT) ? (ks + 2) : (KTOT - 1);  // clamp: dead loads
      #pragma unroll
      for (int j = 0; j < NT; ++j)
        B[ks & 1][j] = bp[(nks*NT + j)*64];
    }
  } else {
    // ---- per-kstep loads (layer-a, NT=9); 4-wave TLP hides latency ----
    #pragma unroll 1
    for (int g = 0; g < NG; ++g) {
      #pragma unroll
      for (int u = 0; u < 8; ++u) {
        const int ks = g*8 + u;
        half8 b[NT];
        #pragma unroll
        for (int j = 0; j < NT; ++j) b[j] = bp[(ks*NT + j)*64];
        half8 A = feat8((float)hinw[ln16*SIN + ks*4 + kg]);
        #pragma unroll
        for (int j = 0; j < NT; ++j)
          acc[j] = __builtin_amdgcn_mfma_f32_16x16x32_f16(A, b[j], acc[j], 0, 0, 0);
      }
    }
    static_assert(KR == 0 || NT <= 4, "layer-a has no remainder");
    #pragma unroll
    for (int sk = 0; sk < KSIL; ++sk) {
      const int ks = KSPL + sk;
      half8 b[NT];
      #pragma unroll
      for (int j = 0; j < NT; ++j) b[j] = bp[(ks*NT + j)*64];
      half8 h8 = *(const half8*)&hinw[ln16*SIN + sk*32 + kg*8];
      union { fp16x2 h2[4]; half8 v; } Au;
      #pragma unroll
      for (int el = 0; el < 4; ++el) {
        float s0 = silu((float)h8[2*el]);
        float s1 = silu((float)h8[2*el + 1]);
        Au.h2[el] = __builtin_amdgcn_cvt_pkrtz(s0, s1);
      }
      #pragma unroll
      for (int j = 0; j < NT; ++j)
        acc[j] = __builtin_amdgcn_mfma_f32_16x16x32_f16(Au.v, b[j], acc[j], 0, 0, 0);
    }
  }

  // ---- epilogue: C/D col=lane&15, row=(lane>>4)*4+reg  [m89-verified] ----
  #pragma unroll
  for (int j = 0; j < NT; ++j) {
    int col = j*16 + ln16;
    if (col < O) {
      float bv = bias[col];
      #pragma unroll
      for (int r = 0; r < 4; ++r)
        houtw[(kg*4 + r)*SOUT + col] = (_Float16)(acc[j][r] + bv);
    }
  }
}

// ---------------------------------------------------------------------------
// fused forward: 16 rows/wave -> 4096 waves -> 4 waves/SIMD (2x TLP vs 32x32).
// Zero barriers; all per-wave independent. LDS = 30208 B; grid 1024 = 4/CU.
// ---------------------------------------------------------------------------
extern "C" __global__ void __launch_bounds__(256, 4)
kan_forward(const float* __restrict__ x, const float* __restrict__ b_in,
            const float* __restrict__ W_out, const _Float16* __restrict__ wt,
            const float* __restrict__ bias0a, const float* __restrict__ bias0b,
            const float* __restrict__ bias1a, const float* __restrict__ bias1b,
            float* __restrict__ out) {
  __shared__ _Float16 hM[4][16*SM];   // 4 x 5376 B
  __shared__ _Float16 hH[4][16*SH];   // 4 x 2176 B
  const int t    = threadIdx.x;
  const int wv   = t >> 6;
  const int lane = t & 63;
  const int ln16 = lane & 15;
  const int kg   = lane >> 4;
  _Float16* hMw = hM[wv];
  _Float16* hHw = hH[wv];
  const int rbase = blockIdx.x * TB + wv * 16;

  // zero hM pad cols 104..167 (cols 104..128 are re-written by layer-a epilogue;
  // 129..167 stay zero: read by layer-b spline remainder + silu tail, B rows zero)
  #pragma unroll
  for (int r = 0; r < 16; ++r) hMw[r*SM + 104 + lane] = (_Float16)0.0f;

  // stage 1: hH = relu(x @ W_in + b_in). One kstep (k=32), 4 n-tiles.
  {
    const float* xr = &x[(size_t)(rbase + ln16)*32 + kg*8];
    float4 v0 = *(const float4*)&xr[0];
    float4 v1 = *(const float4*)&xr[4];
    union { fp16x2 h2[4]; half8 h8; } A;
    A.h2[0] = __builtin_amdgcn_cvt_pkrtz(v0.x, v0.y);
    A.h2[1] = __builtin_amdgcn_cvt_pkrtz(v0.z, v0.w);
    A.h2[2] = __builtin_amdgcn_cvt_pkrtz(v1.x, v1.y);
    A.h2[3] = __builtin_amdgcn_cvt_pkrtz(v1.z, v1.w);
    const half8* bp = (const half8*)wt + lane;
    #pragma unroll
    for (int nt = 0; nt < 4; ++nt) {
      floatx4 a;
      #pragma unroll
      for (int el = 0; el < 4; ++el) a[el] = 0.0f;
      a = __builtin_amdgcn_mfma_f32_16x16x32_f16(A.h8, bp[nt*64], a, 0, 0, 0);
      int col = nt*16 + ln16;
      float bv = b_in[col];
      #pragma unroll
      for (int r = 0; r < 4; ++r)
        hHw[(kg*4 + r)*SH + col] = (_Float16)fmaxf(a[r] + bv, 0.0f);
    }
  }

  kan_layer16<16,2,9,SH,129,SM>(hHw, hMw, wt + WIN,             bias0a, lane);
  kan_layer16<33,5,4,SM, 64,SH>(hMw, hHw, wt + WIN + WA,        bias0b, lane);
  kan_layer16<16,2,9,SH,129,SM>(hHw, hMw, wt + WIN + WA + WB,   bias1a, lane);
  kan_layer16<33,5,4,SM, 64,SH>(hMw, hHw, wt + WIN + 2*WA + WB, bias1b, lane);

  // final: out = sigmoid(hH @ W_out); 4 lanes per row, xor-shuffle reduce
  {
    float s = 0.0f;
    #pragma unroll
    for (int j = 0; j < 16; ++j)
      s = fmaf((float)hHw[ln16*SH + kg*16 + j], W_out[kg*16 + j], s);
    s += __shfl_xor(s, 16);
    s += __shfl_xor(s, 32);
    if (lane < 16)
      out[rbase + ln16] = __builtin_amdgcn_rcpf(1.0f + __expf(-s));
  }
}

// ---------------------------------------------------------------------------
extern "C" void kernel_launch(void* const* d_in, const int* in_sizes, int n_in,
                              void* d_out, int out_size, void* d_ws, size_t ws_size,
                              hipStream_t stream) {
  const float* x     = (const float*)d_in[0];
  const float* W_in  = (const float*)d_in[1];
  const float* b_in  = (const float*)d_in[2];
  const float* W_out = (const float*)d_in[3];
  const float* c0a = (const float*)d_in[4];  const float* sb0a = (const float*)d_in[5];
  const float* ss0a= (const float*)d_in[6];  const float* bias0a=(const float*)d_in[7];
  const float* c0b = (const float*)d_in[8];  const float* sb0b = (const float*)d_in[9];
  const float* ss0b= (const float*)d_in[10]; const float* bias0b=(const float*)d_in[11];
  const float* c1a = (const float*)d_in[12]; const float* sb1a = (const float*)d_in[13];
  const float* ss1a= (const float*)d_in[14]; const float* bias1a=(const float*)d_in[15];
  const float* c1b = (const float*)d_in[16]; const float* sb1b = (const float*)d_in[17];
  const float* ss1b= (const float*)d_in[18]; const float* bias1b=(const float*)d_in[19];
  float*    out = (float*)d_out;
  _Float16* wt  = (_Float16*)d_ws;       // 647,168 B scratch, repacked every call

  setup_weights<<<(WTOT/8 + 255)/256, 256, 0, stream>>>(
      W_in, c0a, sb0a, ss0a, c0b, sb0b, ss0b,
      c1a, sb1a, ss1a, c1b, sb1b, ss1b, wt);

  kan_forward<<<BATCH/TB, 256, 0, stream>>>(
      x, b_in, W_out, wt, bias0a, bias0b, bias1a, bias1b, out);
}

// Round 5
// 155.570 us; speedup vs baseline: 1.1296x; 1.1296x over previous
//
#include <hip/hip_runtime.h>
#include <math.h>
#include <stdint.h>

// ---------------- model constants ----------------
#define BATCH 65536
#define TB 128           // 4 waves x 32 rows (one 32x32 m-tile each), independent

typedef __fp16   fp16x2  __attribute__((ext_vector_type(2)));   // cvt_pkrtz result
typedef _Float16 half8   __attribute__((ext_vector_type(8)));
typedef float    floatx16 __attribute__((ext_vector_type(16)));

// per-wave LDS strides (halves)
#define SH 68            // hH: 64 cols + 4 pad
#define SM 130           // hM: 129 cols + 1
#define HM_SLICE (32*SM + 64)   // +64 zeroed tail halves (b128 overrun, row 31)

// packed-weight geometry (f16), FRAGMENT-ORDERED for 32x32x16:
//   element (ks, nt, lane, j) at ((ks*NT + nt)*512) + lane*8 + j
//   maps to B[k = ks*16 + (lane>>5)*8 + j][n = nt*32 + (lane&31)]
#define WIN 2048          // stage1: 2 ksteps x 2 ntiles x 512
#define KSA 36            // a: 32 spline ksteps + 4 silu
#define KSB 74            // b: 65 spline ksteps (1032 real k) + 9 silu (129 real)
#define WA (KSA*5*512)    // 92160
#define WB (KSB*2*512)    // 75776
#define WTOT (WIN + 2*(WA+WB))   // 337920 halfs = 675840 B of d_ws

// ---------------------------------------------------------------------------
// setup: pack all weights f16 in 32x32-fragment order (same mapping as r12).
// ---------------------------------------------------------------------------
__global__ void setup_weights(
    const float* __restrict__ W_in,
    const float* __restrict__ c0a, const float* __restrict__ sb0a, const float* __restrict__ ss0a,
    const float* __restrict__ c0b, const float* __restrict__ sb0b, const float* __restrict__ ss0b,
    const float* __restrict__ c1a, const float* __restrict__ sb1a, const float* __restrict__ ss1a,
    const float* __restrict__ c1b, const float* __restrict__ sb1b, const float* __restrict__ ss1b,
    _Float16* __restrict__ wt) {
  int idx = blockIdx.x * 256 + threadIdx.x;
  if (idx >= WTOT) return;
  float v = 0.0f;
  if (idx < WIN) {                        // W_in [32][64]: (ks*2+nt)*512 order
    int ks = idx >> 10; int nt = (idx >> 9) & 1;
    int q = idx & 511;  int l = q >> 3;   int j = q & 7;
    int n = nt*32 + (l & 31);
    int k = ks*16 + (l >> 5)*8 + j;
    v = W_in[k*64 + n];
  } else {
    int e2   = idx - WIN;
    int pair = (e2 >= WA + WB) ? 1 : 0;
    int e    = e2 - pair * (WA + WB);
    if (e < WA) {                         // a-type: I=64, O=129 (5 n-tiles)
      const float* coef = pair ? c1a : c0a;
      const float* sb   = pair ? sb1a : sb0a;
      const float* ss   = pair ? ss1a : ss0a;
      int ks = e / 2560; int r = e - ks*2560;
      int nt = r >> 9;   int q = r & 511;
      int l  = q >> 3;   int j = q & 7;
      int n  = nt*32 + (l & 31);
      int k  = ks*16 + (l >> 5)*8 + j;    // k < 576
      if (n < 129) {
        if (k < 512) { int i = k >> 3, p = k & 7; v = ss[i*129+n] * coef[(i*129+n)*8 + p]; }
        else         { int i = k - 512; if (i < 64) v = sb[i*129+n]; }
      }
    } else {                              // b-type: I=129, O=64 (2 n-tiles)
      const float* coef = pair ? c1b : c0b;
      const float* sb   = pair ? sb1b : sb0b;
      const float* ss   = pair ? ss1b : ss0b;
      int eb = e - WA;
      int ks = eb >> 10; int r = eb & 1023;
      int nt = r >> 9;   int q = r & 511;
      int l  = q >> 3;   int j = q & 7;
      int n  = nt*32 + (l & 31);
      int k  = ks*16 + (l >> 5)*8 + j;    // k < 1184
      if (k < 1032)      { int i = k >> 3, p = k & 7; v = ss[i*64+n] * coef[(i*64+n)*8 + p]; }
      else if (k >= 1040){ int s = k - 1040; if (s < 129) v = sb[s*64+n]; }
      // k in [1032,1040) and s >= 129: dead pad slots -> 0
    }
  }
  wt[idx] = (_Float16)v;
}

// ---------------------------------------------------------------------------
// feat8: 8 B-spline basis values of x as a ready A-fragment (8 halfs).
// ---------------------------------------------------------------------------
__device__ __forceinline__ half8 feat8(float x) {
  float s  = fmaf(x, 2.5f, 5.5f);          // (x+2.2)*2.5
  float mf = floorf(s);
  int   m  = (int)mf;
  float u  = s - mf;
  float t  = 1.0f - u;
  float u2 = u*u;
  float t2 = t*t;
  float w0 = t2 * (t * (1.0f/6.0f));
  float w3 = u2 * (u * (1.0f/6.0f));
  float w1 = fmaf(u2, fmaf(0.5f, u, -1.0f), 2.0f/3.0f);   // (3u^3-6u^2+4)/6
  float w2 = fmaf(t2, fmaf(0.5f, t, -1.0f), 2.0f/3.0f);   // symmetry: w1(t)
  union { fp16x2 h2[2]; uint64_t u64; } P;
  P.h2[0] = __builtin_amdgcn_cvt_pkrtz(w0, w1);
  P.h2[1] = __builtin_amdgcn_cvt_pkrtz(w2, w3);
  uint64_t T = ((unsigned)m <= 10u) ? P.u64 : 0ull;
  int A = (m << 4) - 48;                   // bit pos of T in 128-bit window
  uint64_t L  = T << (A & 63);             // valid A: {-48..112} step 16
  uint64_t R_ = T >> ((-A) & 63);
  uint64_t q0 = (A >= 0) ? ((A < 64) ? L : 0ull) : R_;
  uint64_t q1 = (A >= 64) ? L : ((A > 0) ? R_ : 0ull);
  union { uint64_t q[2]; half8 h; } R;
  R.q[0] = q0; R.q[1] = q1;
  return R.h;
}

// extract half #kh of dword w (khs = kh*16), as f32
__device__ __forceinline__ float extract_half(uint32_t w, int khs) {
  union { uint32_t u; _Float16 h[2]; } cv;
  cv.u = w >> khs;
  return (float)cv.h[0];
}

// cheap silu: x * rcp(1+exp(-x)) — v_rcp_f32 (~1 ulp) instead of IEEE div
__device__ __forceinline__ float silu(float x) {
  return x * __builtin_amdgcn_rcpf(1.0f + __expf(-x));
}

// ---------------------------------------------------------------------------
// one KAN layer, per-wave 32 rows = one 32x32 m-tile. A-frags in registers.
// R5 ILP restructure (same math/order as the 68.4us depth-2 baseline):
//  - ksteps processed in PAIRS with BOTH feat8 chains computed before the
//    MFMAs: two independent ~70cy dependency chains in flight instead of one.
//  - next group's h-read (ds_read_b128) prefetched one full group (~400cy)
//    ahead, hiding the ~120cy LDS latency at group starts.
//  - depth-2 zero-copy B pipeline kept (depth-4 measured null in R3).
// ---------------------------------------------------------------------------
template<int KSPL, int KSIL, int NT, int SIN, int O, int SOUT>
__device__ __forceinline__ void kan_layer(
    const _Float16* __restrict__ hinw, _Float16* __restrict__ houtw,
    const _Float16* __restrict__ wt, const float* __restrict__ bias, int lane) {
  constexpr int KTOT = KSPL + KSIL;
  constexpr int NG   = KSPL / 8;            // full spline groups
  constexpr int KR   = KSPL - NG*8;         // remainder spline steps (0 or 1)
  static_assert(KR == 0 || KR == 1, "remainder must be 0/1");
  const int ln  = lane & 31;
  const int kh  = lane >> 5;
  const int khs = kh << 4;
  const half8* __restrict__ bp = (const half8*)wt + lane;   // +lane*16B
  floatx16 acc[NT];
  #pragma unroll
  for (int j = 0; j < NT; ++j)
    #pragma unroll
    for (int e = 0; e < 16; ++e) acc[j][e] = 0.0f;

  half8 B[2][NT];                           // depth-2, zero-copy slots
  #pragma unroll
  for (int d = 0; d < 2; ++d)
    #pragma unroll
    for (int j = 0; j < NT; ++j) B[d][j] = bp[(d*NT + j)*64];

  union H8 { half8 h; uint32_t d[4]; };

  // ---- spline groups: 8 k-steps each; inputs 16g..16g+15 of row ln ----
  // h-reads for group g+1 issued at top of group g's body (prefetch).
  H8 ha, hb;
  ha.h = *(const half8*)&hinw[ln*SIN];
  hb.h = *(const half8*)&hinw[ln*SIN + 8];
  #pragma unroll 1
  for (int g = 0; g < NG; ++g) {
    const int gn = (g + 1 < NG) ? g + 1 : g;       // clamp: dead re-read last iter
    H8 na, nb;
    na.h = *(const half8*)&hinw[ln*SIN + gn*16];
    nb.h = *(const half8*)&hinw[ln*SIN + gn*16 + 8];
    #pragma unroll
    for (int p = 0; p < 4; ++p) {
      const int ks0 = g*8 + 2*p;                   // even kstep -> slot 0
      uint32_t w0 = (p < 2) ? ha.d[2*p]     : hb.d[2*p - 4];
      uint32_t w1 = (p < 2) ? ha.d[2*p + 1] : hb.d[2*p - 3];
      half8 A0 = feat8(extract_half(w0, khs));     // input i = 2*ks0+kh
      half8 A1 = feat8(extract_half(w1, khs));     // input i = 2*ks0+2+kh
      #pragma unroll
      for (int j = 0; j < NT; ++j)
        acc[j] = __builtin_amdgcn_mfma_f32_32x32x16_f16(A0, B[0][j], acc[j], 0, 0, 0);
      #pragma unroll
      for (int j = 0; j < NT; ++j)                 // refill slot 0 with ks0+2
        B[0][j] = bp[((ks0 + 2)*NT + j)*64];
      #pragma unroll
      for (int j = 0; j < NT; ++j)
        acc[j] = __builtin_amdgcn_mfma_f32_32x32x16_f16(A1, B[1][j], acc[j], 0, 0, 0);
      #pragma unroll
      for (int j = 0; j < NT; ++j)                 // refill slot 1 with ks0+3
        B[1][j] = bp[((ks0 + 3)*NT + j)*64];       // max 8*NG+1 <= KTOT-1
    }
    ha = na; hb = nb;
  }

  // ---- remainder spline step (layer-b: ks = NG*8) ----
  if (KR == 1) {
    constexpr int ks = NG*8;
    H8 hc;
    hc.h = *(const half8*)&hinw[ln*SIN + ks*2];  // elems 2ks..2ks+7 (pads zeroed)
    half8 A = feat8(extract_half(hc.d[0], khs));
    #pragma unroll
    for (int j = 0; j < NT; ++j)
      acc[j] = __builtin_amdgcn_mfma_f32_32x32x16_f16(A, B[ks & 1][j], acc[j], 0, 0, 0);
    #pragma unroll
    for (int j = 0; j < NT; ++j)
      B[ks & 1][j] = bp[((ks + 2)*NT + j)*64];   // ks+2 < KTOT (KSIL >= 9 here)
  }

  // ---- silu k-steps (fully unrolled; slots compile-time) ----
  #pragma unroll
  for (int sk = 0; sk < KSIL; ++sk) {
    const int ks = KSPL + sk;
    half8 h8 = *(const half8*)&hinw[ln*SIN + sk*16 + kh*8];
    union { fp16x2 h2[4]; half8 v; } Au;
    #pragma unroll
    for (int e = 0; e < 4; ++e) {
      float s0 = silu((float)h8[2*e]);
      float s1 = silu((float)h8[2*e + 1]);
      Au.h2[e] = __builtin_amdgcn_cvt_pkrtz(s0, s1);
    }
    #pragma unroll
    for (int j = 0; j < NT; ++j)
      acc[j] = __builtin_amdgcn_mfma_f32_32x32x16_f16(Au.v, B[ks & 1][j], acc[j], 0, 0, 0);
    const int nks = (ks + 2 < KTOT) ? (ks + 2) : (KTOT - 1);
    #pragma unroll
    for (int j = 0; j < NT; ++j)
      B[ks & 1][j] = bp[(nks*NT + j)*64];
  }

  // ---- epilogue: C/D col=lane&31, row=(reg&3)+8*(reg>>2)+4*(lane>>5) ----
  #pragma unroll
  for (int j = 0; j < NT; ++j) {
    int col = j*32 + ln;
    if (col < O) {
      float bv = bias[col];
      #pragma unroll
      for (int r = 0; r < 16; ++r) {
        int row = (r & 3) + 8*(r >> 2) + 4*kh;
        houtw[row*SOUT + col] = (_Float16)(acc[j][r] + bv);
      }
    }
  }
}

// ---------------------------------------------------------------------------
// fused forward, zero __syncthreads, 32x32 MFMA, zero-copy depth-2 pipeline.
// LDS = 51200 B -> 2 blocks/CU; grid 512 = exact.
// ---------------------------------------------------------------------------
extern "C" __global__ void __launch_bounds__(256, 2)
kan_forward(const float* __restrict__ x, const float* __restrict__ b_in,
            const float* __restrict__ W_out, const _Float16* __restrict__ wt,
            const float* __restrict__ bias0a, const float* __restrict__ bias0b,
            const float* __restrict__ bias1a, const float* __restrict__ bias1b,
            float* __restrict__ out) {
  __shared__ _Float16 hM[4][HM_SLICE];
  __shared__ _Float16 hH[4][32*SH];
  const int t    = threadIdx.x;
  const int wv   = t >> 6;
  const int lane = t & 63;
  const int ln   = lane & 31;
  const int kh   = lane >> 5;
  _Float16* hMw = hM[wv];
  _Float16* hHw = hH[wv];
  const int rbase = blockIdx.x * TB + wv * 32;

  // zero hM spots padded reads can touch: col 129 each row + tail pad
  hMw[32*SM + lane] = (_Float16)0.0f;
  if (lane < 32) hMw[lane*SM + 129] = (_Float16)0.0f;

  // stage 1: hH = relu(x @ W_in + b_in). Two k-steps, 2 n-tiles.
  {
    const float* xr = &x[(rbase + ln)*32 + kh*8];
    float4 v0 = *(const float4*)&xr[0];
    float4 v1 = *(const float4*)&xr[4];
    float4 v2 = *(const float4*)&xr[16];
    float4 v3 = *(const float4*)&xr[20];
    union { fp16x2 h2[4]; half8 h8; } A0, A1;
    A0.h2[0] = __builtin_amdgcn_cvt_pkrtz(v0.x, v0.y);
    A0.h2[1] = __builtin_amdgcn_cvt_pkrtz(v0.z, v0.w);
    A0.h2[2] = __builtin_amdgcn_cvt_pkrtz(v1.x, v1.y);
    A0.h2[3] = __builtin_amdgcn_cvt_pkrtz(v1.z, v1.w);
    A1.h2[0] = __builtin_amdgcn_cvt_pkrtz(v2.x, v2.y);
    A1.h2[1] = __builtin_amdgcn_cvt_pkrtz(v2.z, v2.w);
    A1.h2[2] = __builtin_amdgcn_cvt_pkrtz(v3.x, v3.y);
    A1.h2[3] = __builtin_amdgcn_cvt_pkrtz(v3.z, v3.w);
    const half8* bp = (const half8*)wt + lane;
    #pragma unroll
    for (int nt = 0; nt < 2; ++nt) {
      floatx16 a;
      #pragma unroll
      for (int e = 0; e < 16; ++e) a[e] = 0.0f;
      a = __builtin_amdgcn_mfma_f32_32x32x16_f16(A0.h8, bp[nt*64],       a, 0, 0, 0);
      a = __builtin_amdgcn_mfma_f32_32x32x16_f16(A1.h8, bp[(2 + nt)*64], a, 0, 0, 0);
      int col = nt*32 + ln;
      float bv = b_in[col];
      #pragma unroll
      for (int r = 0; r < 16; ++r) {
        int row = (r & 3) + 8*(r >> 2) + 4*kh;
        hHw[row*SH + col] = (_Float16)fmaxf(a[r] + bv, 0.0f);
      }
    }
  }

  kan_layer<32,4,5,SH,129,SM>(hHw, hMw, wt + WIN,             bias0a, lane);
  kan_layer<65,9,2,SM, 64,SH>(hMw, hHw, wt + WIN + WA,        bias0b, lane);
  kan_layer<32,4,5,SH,129,SM>(hHw, hMw, wt + WIN + WA + WB,   bias1a, lane);
  kan_layer<65,9,2,SM, 64,SH>(hMw, hHw, wt + WIN + 2*WA + WB, bias1b, lane);

  // final: out = sigmoid(hH @ W_out); two col-halves reduced by shuffle
  {
    float s = 0.0f;
    #pragma unroll
    for (int j = 0; j < 32; ++j)
      s = fmaf((float)hHw[ln*SH + kh*32 + j], W_out[kh*32 + j], s);
    s += __shfl_down(s, 32);
    if (lane < 32)
      out[rbase + ln] = __builtin_amdgcn_rcpf(1.0f + __expf(-s));
  }
}

// ---------------------------------------------------------------------------
extern "C" void kernel_launch(void* const* d_in, const int* in_sizes, int n_in,
                              void* d_out, int out_size, void* d_ws, size_t ws_size,
                              hipStream_t stream) {
  const float* x     = (const float*)d_in[0];
  const float* W_in  = (const float*)d_in[1];
  const float* b_in  = (const float*)d_in[2];
  const float* W_out = (const float*)d_in[3];
  const float* c0a = (const float*)d_in[4];  const float* sb0a = (const float*)d_in[5];
  const float* ss0a= (const float*)d_in[6];  const float* bias0a=(const float*)d_in[7];
  const float* c0b = (const float*)d_in[8];  const float* sb0b = (const float*)d_in[9];
  const float* ss0b= (const float*)d_in[10]; const float* bias0b=(const float*)d_in[11];
  const float* c1a = (const float*)d_in[12]; const float* sb1a = (const float*)d_in[13];
  const float* ss1a= (const float*)d_in[14]; const float* bias1a=(const float*)d_in[15];
  const float* c1b = (const float*)d_in[16]; const float* sb1b = (const float*)d_in[17];
  const float* ss1b= (const float*)d_in[18]; const float* bias1b=(const float*)d_in[19];
  float*    out = (float*)d_out;
  _Float16* wt  = (_Float16*)d_ws;       // 675,840 B scratch, repacked every call

  setup_weights<<<(WTOT + 255)/256, 256, 0, stream>>>(
      W_in, c0a, sb0a, ss0a, c0b, sb0b, ss0b,
      c1a, sb1a, ss1a, c1b, sb1b, ss1b, wt);

  kan_forward<<<BATCH/TB, 256, 0, stream>>>(
      x, b_in, W_out, wt, bias0a, bias0b, bias1a, bias1b, out);
}